// Round 1
// baseline (31456.970 us; speedup 1.0000x reference)
//
#include <hip/hip_runtime.h>
#include <hip/hip_cooperative_groups.h>

namespace cg = cooperative_groups;

#define T_STEPS 512
#define BATCH   64
#define EDIM    256
#define HDIM    512

// ---------- activation helpers (fast, clamped to avoid inf/NaN) ----------
__device__ __forceinline__ float sigm(float x) {
    x = fminf(fmaxf(x, -30.f), 30.f);
    return 1.f / (1.f + __expf(-x));
}
__device__ __forceinline__ float tanh_f(float x) {
    x = fminf(fmaxf(x, -15.f), 15.f);
    float e = __expf(2.f * x);
    return (e - 1.f) / (e + 1.f);
}

// ---------- pre-kernel: gather embeddings transposed ----------
// XeT[t][k][b] = emb[x[b][t]][k]   (so per-step reads are coalesced 256B rows)
__global__ __launch_bounds__(256) void xet_kernel(const int* __restrict__ x,
                                                  const float* __restrict__ emb,
                                                  float* __restrict__ XeT) {
    __shared__ float nat[BATCH][EDIM + 1];
    const int t   = blockIdx.x;
    const int tid = threadIdx.x;
    // load: each pass reads one emb row (1KB, coalesced)
    for (int b = 0; b < BATCH; ++b) {
        int idx = x[b * T_STEPS + t];
        nat[b][tid] = emb[(size_t)idx * EDIM + tid];
    }
    __syncthreads();
    // store transposed: o = k*64 + b, coalesced global writes
    float* dst = XeT + (size_t)t * (EDIM * BATCH);
    for (int rep = 0; rep < 64; ++rep) {
        int o = rep * 256 + tid;
        int k = o >> 6;
        int b = o & 63;
        dst[o] = nat[b][k];
    }
}

// ---------- zero-init for state (ws is poisoned 0xAA before every call) ----------
__global__ void zero_kernel(float* __restrict__ p, int n) {
    int i = blockIdx.x * blockDim.x + threadIdx.x;
    if (i < n) p[i] = 0.f;
}

// ---------- main persistent cooperative kernel ----------
// grid = 256 blocks x 256 threads = 1024 waves.
// waves 0..511   : layer0, column j = gwave      (computes step p in phase p)
// waves 512..1023: layer1, column j = gwave-512  (computes step p-1 in phase p)
// State layouts are transposed [k][b] (b fastest) for coalescing.
__global__ __launch_bounds__(256) void lstm_main(
    const float* __restrict__ XeT,
    const float* __restrict__ Wih0, const float* __restrict__ Whh0, const float* __restrict__ bias0,
    const float* __restrict__ Wih1, const float* __restrict__ Whh1, const float* __restrict__ bias1,
    const float* __restrict__ Wclf, const float* __restrict__ bclf,
    float* __restrict__ h0b, float* __restrict__ h1b,
    float* __restrict__ c0,  float* __restrict__ c1,
    float* __restrict__ out)
{
    cg::grid_group grid = cg::this_grid();
    const int lane  = threadIdx.x & 63;
    const int gwave = (blockIdx.x * blockDim.x + threadIdx.x) >> 6;
    const int HB = HDIM * BATCH;

    for (int p = 0; p <= T_STEPS; ++p) {
        const int par = p & 1;
        const float* h0r = h0b + (par ^ 1) * HB;   // h0[step p-1]
        float*       h0w = h0b + par * HB;         // h0[step p]
        const float* h1r = h1b + (par ^ 1) * HB;   // h1[step p-2]
        float*       h1w = h1b + par * HB;         // h1[step p-1]

        if (gwave < HDIM) {
            // ---------------- layer 0, step p ----------------
            if (p < T_STEPS) {
                const int j = __builtin_amdgcn_readfirstlane(gwave);
                const float4* wi0 = (const float4*)(Wih0 + (size_t)(0 * HDIM + j) * EDIM);
                const float4* wi1 = (const float4*)(Wih0 + (size_t)(1 * HDIM + j) * EDIM);
                const float4* wi2 = (const float4*)(Wih0 + (size_t)(2 * HDIM + j) * EDIM);
                const float4* wi3 = (const float4*)(Wih0 + (size_t)(3 * HDIM + j) * EDIM);
                const float4* wh0 = (const float4*)(Whh0 + (size_t)(0 * HDIM + j) * HDIM);
                const float4* wh1 = (const float4*)(Whh0 + (size_t)(1 * HDIM + j) * HDIM);
                const float4* wh2 = (const float4*)(Whh0 + (size_t)(2 * HDIM + j) * HDIM);
                const float4* wh3 = (const float4*)(Whh0 + (size_t)(3 * HDIM + j) * HDIM);

                float a0 = bias0[j];
                float a1 = bias0[HDIM + j];
                float a2 = bias0[2 * HDIM + j];
                float a3 = bias0[3 * HDIM + j];

                const float* xe = XeT + (size_t)p * (EDIM * BATCH) + lane;
                #pragma unroll 2
                for (int k4 = 0; k4 < EDIM / 4; ++k4) {
                    float v0 = xe[(4 * k4 + 0) * BATCH];
                    float v1 = xe[(4 * k4 + 1) * BATCH];
                    float v2 = xe[(4 * k4 + 2) * BATCH];
                    float v3 = xe[(4 * k4 + 3) * BATCH];
                    float4 w0 = wi0[k4], w1 = wi1[k4], w2 = wi2[k4], w3 = wi3[k4];
                    a0 = fmaf(v0, w0.x, a0); a0 = fmaf(v1, w0.y, a0); a0 = fmaf(v2, w0.z, a0); a0 = fmaf(v3, w0.w, a0);
                    a1 = fmaf(v0, w1.x, a1); a1 = fmaf(v1, w1.y, a1); a1 = fmaf(v2, w1.z, a1); a1 = fmaf(v3, w1.w, a1);
                    a2 = fmaf(v0, w2.x, a2); a2 = fmaf(v1, w2.y, a2); a2 = fmaf(v2, w2.z, a2); a2 = fmaf(v3, w2.w, a2);
                    a3 = fmaf(v0, w3.x, a3); a3 = fmaf(v1, w3.y, a3); a3 = fmaf(v2, w3.z, a3); a3 = fmaf(v3, w3.w, a3);
                }
                const float* hr = h0r + lane;
                #pragma unroll 2
                for (int k4 = 0; k4 < HDIM / 4; ++k4) {
                    float v0 = hr[(4 * k4 + 0) * BATCH];
                    float v1 = hr[(4 * k4 + 1) * BATCH];
                    float v2 = hr[(4 * k4 + 2) * BATCH];
                    float v3 = hr[(4 * k4 + 3) * BATCH];
                    float4 w0 = wh0[k4], w1 = wh1[k4], w2 = wh2[k4], w3 = wh3[k4];
                    a0 = fmaf(v0, w0.x, a0); a0 = fmaf(v1, w0.y, a0); a0 = fmaf(v2, w0.z, a0); a0 = fmaf(v3, w0.w, a0);
                    a1 = fmaf(v0, w1.x, a1); a1 = fmaf(v1, w1.y, a1); a1 = fmaf(v2, w1.z, a1); a1 = fmaf(v3, w1.w, a1);
                    a2 = fmaf(v0, w2.x, a2); a2 = fmaf(v1, w2.y, a2); a2 = fmaf(v2, w2.z, a2); a2 = fmaf(v3, w2.w, a2);
                    a3 = fmaf(v0, w3.x, a3); a3 = fmaf(v1, w3.y, a3); a3 = fmaf(v2, w3.z, a3); a3 = fmaf(v3, w3.w, a3);
                }
                float cp = c0[j * BATCH + lane];
                float ig = sigm(a0), fg = sigm(a1), gg = tanh_f(a2), og = sigm(a3);
                float cn = fg * cp + ig * gg;
                float hn = og * tanh_f(cn);
                c0[j * BATCH + lane]  = cn;
                h0w[j * BATCH + lane] = hn;
            }
        } else {
            // ---------------- layer 1, step p-1 ----------------
            if (p >= 1) {
                const int j = __builtin_amdgcn_readfirstlane(gwave - HDIM);
                const float4* wi0 = (const float4*)(Wih1 + (size_t)(0 * HDIM + j) * HDIM);
                const float4* wi1 = (const float4*)(Wih1 + (size_t)(1 * HDIM + j) * HDIM);
                const float4* wi2 = (const float4*)(Wih1 + (size_t)(2 * HDIM + j) * HDIM);
                const float4* wi3 = (const float4*)(Wih1 + (size_t)(3 * HDIM + j) * HDIM);
                const float4* wh0 = (const float4*)(Whh1 + (size_t)(0 * HDIM + j) * HDIM);
                const float4* wh1 = (const float4*)(Whh1 + (size_t)(1 * HDIM + j) * HDIM);
                const float4* wh2 = (const float4*)(Whh1 + (size_t)(2 * HDIM + j) * HDIM);
                const float4* wh3 = (const float4*)(Whh1 + (size_t)(3 * HDIM + j) * HDIM);

                float a0 = bias1[j];
                float a1 = bias1[HDIM + j];
                float a2 = bias1[2 * HDIM + j];
                float a3 = bias1[3 * HDIM + j];

                const float* xr = h0r + lane;   // input = h0 of step p-1
                #pragma unroll 2
                for (int k4 = 0; k4 < HDIM / 4; ++k4) {
                    float v0 = xr[(4 * k4 + 0) * BATCH];
                    float v1 = xr[(4 * k4 + 1) * BATCH];
                    float v2 = xr[(4 * k4 + 2) * BATCH];
                    float v3 = xr[(4 * k4 + 3) * BATCH];
                    float4 w0 = wi0[k4], w1 = wi1[k4], w2 = wi2[k4], w3 = wi3[k4];
                    a0 = fmaf(v0, w0.x, a0); a0 = fmaf(v1, w0.y, a0); a0 = fmaf(v2, w0.z, a0); a0 = fmaf(v3, w0.w, a0);
                    a1 = fmaf(v0, w1.x, a1); a1 = fmaf(v1, w1.y, a1); a1 = fmaf(v2, w1.z, a1); a1 = fmaf(v3, w1.w, a1);
                    a2 = fmaf(v0, w2.x, a2); a2 = fmaf(v1, w2.y, a2); a2 = fmaf(v2, w2.z, a2); a2 = fmaf(v3, w2.w, a2);
                    a3 = fmaf(v0, w3.x, a3); a3 = fmaf(v1, w3.y, a3); a3 = fmaf(v2, w3.z, a3); a3 = fmaf(v3, w3.w, a3);
                }
                const float* hr = h1r + lane;   // h1 of step p-2
                #pragma unroll 2
                for (int k4 = 0; k4 < HDIM / 4; ++k4) {
                    float v0 = hr[(4 * k4 + 0) * BATCH];
                    float v1 = hr[(4 * k4 + 1) * BATCH];
                    float v2 = hr[(4 * k4 + 2) * BATCH];
                    float v3 = hr[(4 * k4 + 3) * BATCH];
                    float4 w0 = wh0[k4], w1 = wh1[k4], w2 = wh2[k4], w3 = wh3[k4];
                    a0 = fmaf(v0, w0.x, a0); a0 = fmaf(v1, w0.y, a0); a0 = fmaf(v2, w0.z, a0); a0 = fmaf(v3, w0.w, a0);
                    a1 = fmaf(v0, w1.x, a1); a1 = fmaf(v1, w1.y, a1); a1 = fmaf(v2, w1.z, a1); a1 = fmaf(v3, w1.w, a1);
                    a2 = fmaf(v0, w2.x, a2); a2 = fmaf(v1, w2.y, a2); a2 = fmaf(v2, w2.z, a2); a2 = fmaf(v3, w2.w, a2);
                    a3 = fmaf(v0, w3.x, a3); a3 = fmaf(v1, w3.y, a3); a3 = fmaf(v2, w3.z, a3); a3 = fmaf(v3, w3.w, a3);
                }
                float cp = c1[j * BATCH + lane];
                float ig = sigm(a0), fg = sigm(a1), gg = tanh_f(a2), og = sigm(a3);
                float cn = fg * cp + ig * gg;
                float hn = og * tanh_f(cn);
                c1[j * BATCH + lane]  = cn;
                h1w[j * BATCH + lane] = hn;
            }
        }
        grid.sync();
    }

    // classifier: final h1 was written in phase T (parity 0) -> h1b + 0
    if (gwave < 2) {
        const int o = gwave;
        float acc = bclf[o];
        const float* hf = h1b + lane;
        const float* wc = Wclf + o * HDIM;
        #pragma unroll 4
        for (int k = 0; k < HDIM; ++k) acc = fmaf(hf[k * BATCH], wc[k], acc);
        out[lane * 2 + o] = acc;
    }
}

extern "C" void kernel_launch(void* const* d_in, const int* in_sizes, int n_in,
                              void* d_out, int out_size, void* d_ws, size_t ws_size,
                              hipStream_t stream) {
    const int*   x     = (const int*)d_in[0];
    const float* emb   = (const float*)d_in[1];
    const float* Wih0  = (const float*)d_in[2];
    const float* Whh0  = (const float*)d_in[3];
    const float* bias0 = (const float*)d_in[4];
    const float* Wih1  = (const float*)d_in[5];
    const float* Whh1  = (const float*)d_in[6];
    const float* bias1 = (const float*)d_in[7];
    const float* Wclf  = (const float*)d_in[8];
    const float* bclf  = (const float*)d_in[9];
    float* out = (float*)d_out;

    // workspace layout (floats): XeT | h0b(x2) | h1b(x2) | c0 | c1  (~33 MB)
    float* XeT = (float*)d_ws;
    float* h0b = XeT + (size_t)T_STEPS * EDIM * BATCH;   // 2 * 512*64
    float* h1b = h0b + 2 * HDIM * BATCH;
    float* c0  = h1b + 2 * HDIM * BATCH;
    float* c1  = c0 + HDIM * BATCH;

    // 1) gather embeddings transposed
    xet_kernel<<<T_STEPS, 256, 0, stream>>>(x, emb, XeT);
    // 2) zero h/c state (contiguous 6*HDIM*BATCH floats starting at h0b)
    zero_kernel<<<768, 256, 0, stream>>>(h0b, 6 * HDIM * BATCH);
    // 3) persistent cooperative LSTM
    void* args[] = {
        (void*)&XeT,
        (void*)&Wih0, (void*)&Whh0, (void*)&bias0,
        (void*)&Wih1, (void*)&Whh1, (void*)&bias1,
        (void*)&Wclf, (void*)&bclf,
        (void*)&h0b, (void*)&h1b, (void*)&c0, (void*)&c1,
        (void*)&out
    };
    hipLaunchCooperativeKernel((void*)lstm_main, dim3(256), dim3(256), args, 0, stream);
}

// Round 4
// 19458.073 us; speedup vs baseline: 1.6167x; 1.6167x over previous
//
#include <hip/hip_runtime.h>
#include <hip/hip_cooperative_groups.h>

namespace cg = cooperative_groups;

#define T_STEPS 512
#define BATCH   64
#define EDIM    256
#define HDIM    512
#define HB      (BATCH * HDIM)          // elements of one h-state slot (32768)

typedef __attribute__((ext_vector_type(8))) short  bf16x8;
typedef __attribute__((ext_vector_type(4))) float  f32x4;
typedef unsigned short ushort_t;

// ---------- bf16 helpers ----------
__device__ __forceinline__ unsigned short f2bf(float x) {
    unsigned u = __float_as_uint(x);
    u += 0x7fffu + ((u >> 16) & 1u);
    return (unsigned short)(u >> 16);
}
__device__ __forceinline__ float bf2f(unsigned short h) {
    return __uint_as_float(((unsigned)h) << 16);
}

// ---------- activations ----------
__device__ __forceinline__ float sigm(float x) {
    x = fminf(fmaxf(x, -30.f), 30.f);
    return 1.f / (1.f + __expf(-x));
}
__device__ __forceinline__ float tanh_f(float x) {
    x = fminf(fmaxf(x, -15.f), 15.f);
    float e = __expf(2.f * x);
    return (e - 1.f) / (e + 1.f);
}

// workspace layout (ushort elements)  -- total ~32.0 MB (round-1 proved >=34 MB available)
#define OFF_XEHI  ((size_t)0)
#define SZ_XEHI   ((size_t)T_STEPS * BATCH * EDIM)          // 8388608
#define OFF_H0HI  (OFF_XEHI + SZ_XEHI)
#define OFF_H0LO  (OFF_H0HI + 2 * HB)
#define OFF_H1HI  (OFF_H0LO + 2 * HB)
#define OFF_H1LO  (OFF_H1HI + 2 * HB)
#define OFF_B0HI  (OFF_H1LO + 2 * HB)
#define SZ_BPK0   ((size_t)32 * 4 * 24 * 64 * 8)            // 1572864
#define OFF_B0LO  (OFF_B0HI + SZ_BPK0)
#define OFF_B1HI  (OFF_B0LO + SZ_BPK0)
#define SZ_BPK1   ((size_t)32 * 4 * 32 * 64 * 8)            // 2097152
#define OFF_B1LO  (OFF_B1HI + SZ_BPK1)

// ---------- prep: gather embeddings -> bf16 row-major [t][b][256] ----------
__global__ __launch_bounds__(256) void xepack_kernel(const int* __restrict__ x,
                                                     const float* __restrict__ emb,
                                                     ushort_t* __restrict__ XeHi) {
    int tid = blockIdx.x * 256 + threadIdx.x;          // 1,048,576 threads
    int c8 = tid & 31;
    int b  = (tid >> 5) & 63;
    int t  = tid >> 11;
    int idx = x[b * T_STEPS + t];
    const float4* e = (const float4*)(emb + (size_t)idx * EDIM + c8 * 8);
    float4 f0 = e[0], f1 = e[1];
    ushort_t v[8];
    v[0] = f2bf(f0.x); v[1] = f2bf(f0.y); v[2] = f2bf(f0.z); v[3] = f2bf(f0.w);
    v[4] = f2bf(f1.x); v[5] = f2bf(f1.y); v[6] = f2bf(f1.z); v[7] = f2bf(f1.w);
    ushort_t* dst = XeHi + ((size_t)t * BATCH + b) * EDIM + c8 * 8;
    *(uint4*)dst = *(uint4*)v;
}

// ---------- prep: pack weights into B-fragment order, bf16 hi/lo pair ----------
// Bpk flat index: (((u*4 + g)*KS + ks)*64 + lane)*8, element j:
//   k = ks*32 + (lane>>4)*8 + j, col n = g*512 + u*16 + (lane&15), value W[n][k]
__global__ __launch_bounds__(256) void wpack_kernel(const float* __restrict__ Wih0, const float* __restrict__ Whh0,
                                                    const float* __restrict__ Wih1, const float* __restrict__ Whh1,
                                                    ushort_t* __restrict__ B0hi, ushort_t* __restrict__ B0lo,
                                                    ushort_t* __restrict__ B1hi, ushort_t* __restrict__ B1lo) {
    const int NT0 = 32 * 4 * 24 * 64;   // 196608
    const int NT1 = 32 * 4 * 32 * 64;   // 262144
    int tid = blockIdx.x * 256 + threadIdx.x;
    if (tid >= NT0 + NT1) return;
    int layer, idx, KS;
    ushort_t *dhi, *dlo;
    if (tid < NT0) { layer = 0; idx = tid;        KS = 24; dhi = B0hi; dlo = B0lo; }
    else           { layer = 1; idx = tid - NT0;  KS = 32; dhi = B1hi; dlo = B1lo; }
    int lane = idx & 63;
    int t1 = idx >> 6;
    int ks = t1 % KS;
    int t2 = t1 / KS;
    int g = t2 & 3;
    int u = t2 >> 2;
    int n = g * HDIM + u * 16 + (lane & 15);
    int k = ks * 32 + (lane >> 4) * 8;
    const float* src;
    if (layer == 0) src = (k < EDIM) ? (Wih0 + (size_t)n * EDIM + k) : (Whh0 + (size_t)n * HDIM + (k - EDIM));
    else            src = (k < HDIM) ? (Wih1 + (size_t)n * HDIM + k) : (Whh1 + (size_t)n * HDIM + (k - HDIM));
    const float4* s4 = (const float4*)src;
    float4 f0 = s4[0], f1 = s4[1];
    float f[8] = {f0.x, f0.y, f0.z, f0.w, f1.x, f1.y, f1.z, f1.w};
    ushort_t vh[8], vl[8];
    #pragma unroll
    for (int j = 0; j < 8; ++j) {
        vh[j] = f2bf(f[j]);
        vl[j] = f2bf(f[j] - bf2f(vh[j]));
    }
    *(uint4*)(dhi + (size_t)idx * 8) = *(uint4*)vh;
    *(uint4*)(dlo + (size_t)idx * 8) = *(uint4*)vl;
}

// ---------- prep: zero the h-state buffers ----------
__global__ void zero_kernel(unsigned int* __restrict__ p, int n) {
    int i = blockIdx.x * blockDim.x + threadIdx.x;
    if (i < n) p[i] = 0u;
}

// ---------- main persistent cooperative kernel ----------
// 256 WGs x 128 threads (2 waves). WG w: layer = w>>7; u=(w>>2)&31; bt=w&3.
// wave0 = K-lower half (owner: c-state, elementwise, h write); wave1 = K-upper half.
__global__ __launch_bounds__(128, 1) void lstm_main(
    const ushort_t* __restrict__ XeHi,
    ushort_t* __restrict__ H0hi, ushort_t* __restrict__ H0lo,
    ushort_t* __restrict__ H1hi, ushort_t* __restrict__ H1lo,
    const ushort_t* __restrict__ B0hi, const ushort_t* __restrict__ B0lo,
    const ushort_t* __restrict__ B1hi, const ushort_t* __restrict__ B1lo,
    const float* __restrict__ bias0, const float* __restrict__ bias1,
    const float* __restrict__ Wclf, const float* __restrict__ bclf,
    float* __restrict__ out)
{
    cg::grid_group grid = cg::this_grid();
    __shared__ float red[4][4][64];

    const int lane = threadIdx.x & 63;
    const int wv   = threadIdx.x >> 6;          // 0 or 1
    const int wg   = blockIdx.x;
    const int layer = wg >> 7;
    const int rr   = wg & 127;
    const int u    = rr >> 2;
    const int bt   = rr & 3;
    const int KS   = layer ? 32 : 24;
    const int ksBeg = wv ? KS / 2 : 0;
    const int ksEnd = wv ? KS : KS / 2;
    const ushort_t* Bhi = layer ? B1hi : B0hi;
    const ushort_t* Blo = layer ? B1lo : B0lo;
    const float* bias   = layer ? bias1 : bias0;

    // hoisted per-lane constants
    const int rowA = bt * 16 + (lane & 15);     // batch row for A-frags
    const int koffA = (lane >> 4) * 8;
    const size_t bBase = (size_t)(u * 4) * KS * 512 + (size_t)lane * 8;  // + (g*KS+ks)*512
    float bg0 = bias[0 * HDIM + u * 16 + (lane & 15)];
    float bg1 = bias[1 * HDIM + u * 16 + (lane & 15)];
    float bg2 = bias[2 * HDIM + u * 16 + (lane & 15)];
    float bg3 = bias[3 * HDIM + u * 16 + (lane & 15)];

    f32x4 cst = {0.f, 0.f, 0.f, 0.f};           // persistent c-state (owner wave)

    for (int p = 0; p <= T_STEPS; ++p) {
        const bool active = layer ? (p >= 1) : (p < T_STEPS);
        f32x4 acc0 = {0,0,0,0}, acc1 = {0,0,0,0}, acc2 = {0,0,0,0}, acc3 = {0,0,0,0};

        if (active) {
            // ---- resolve + load one k-step's fragments ----
            auto loadA = [&](int ks, bf16x8& ah, bf16x8& al, int& haslo) {
                const ushort_t* hi; const ushort_t* lo = nullptr; int ld, kl;
                if (layer == 0) {
                    if (ks < 8) { hi = XeHi + (size_t)p * (BATCH * EDIM); ld = EDIM; kl = ks; }
                    else { int s = (p - 1) & 1; hi = H0hi + (size_t)s * HB; lo = H0lo + (size_t)s * HB; ld = HDIM; kl = ks - 8; }
                } else {
                    if (ks < 16) { int s = (p - 1) & 1; hi = H0hi + (size_t)s * HB; lo = H0lo + (size_t)s * HB; ld = HDIM; kl = ks; }
                    else         { int s = p & 1;       hi = H1hi + (size_t)s * HB; lo = H1lo + (size_t)s * HB; ld = HDIM; kl = ks - 16; }
                }
                size_t off = (size_t)rowA * ld + kl * 32 + koffA;
                ah = *(const bf16x8*)(hi + off);
                haslo = (lo != nullptr);
                if (lo) al = *(const bf16x8*)(lo + off);
            };
            auto loadB = [&](int ks, bf16x8* bh, bf16x8* bl) {
                const size_t gs = (size_t)KS * 512;
                const size_t o  = bBase + (size_t)ks * 512;
                #pragma unroll
                for (int g = 0; g < 4; ++g) {
                    bh[g] = *(const bf16x8*)(Bhi + o + g * gs);
                    bl[g] = *(const bf16x8*)(Blo + o + g * gs);
                }
            };

            bf16x8 cah, cal, cbh[4], cbl[4]; int chl;
            loadA(ksBeg, cah, cal, chl);
            loadB(ksBeg, cbh, cbl);
            #pragma unroll 2
            for (int ks = ksBeg; ks < ksEnd; ++ks) {
                bf16x8 nah = cah, nal = cal, nbh[4], nbl[4]; int nhl = chl;
                #pragma unroll
                for (int g = 0; g < 4; ++g) { nbh[g] = cbh[g]; nbl[g] = cbl[g]; }
                if (ks + 1 < ksEnd) {
                    loadA(ks + 1, nah, nal, nhl);
                    loadB(ks + 1, nbh, nbl);
                }
                // 3-term products: hi*hi + hi*lo + lo*hi  (lo*lo dropped, ~2^-18)
                acc0 = __builtin_amdgcn_mfma_f32_16x16x32_bf16(cah, cbh[0], acc0, 0, 0, 0);
                acc1 = __builtin_amdgcn_mfma_f32_16x16x32_bf16(cah, cbh[1], acc1, 0, 0, 0);
                acc2 = __builtin_amdgcn_mfma_f32_16x16x32_bf16(cah, cbh[2], acc2, 0, 0, 0);
                acc3 = __builtin_amdgcn_mfma_f32_16x16x32_bf16(cah, cbh[3], acc3, 0, 0, 0);
                acc0 = __builtin_amdgcn_mfma_f32_16x16x32_bf16(cah, cbl[0], acc0, 0, 0, 0);
                acc1 = __builtin_amdgcn_mfma_f32_16x16x32_bf16(cah, cbl[1], acc1, 0, 0, 0);
                acc2 = __builtin_amdgcn_mfma_f32_16x16x32_bf16(cah, cbl[2], acc2, 0, 0, 0);
                acc3 = __builtin_amdgcn_mfma_f32_16x16x32_bf16(cah, cbl[3], acc3, 0, 0, 0);
                if (chl) {
                    acc0 = __builtin_amdgcn_mfma_f32_16x16x32_bf16(cal, cbh[0], acc0, 0, 0, 0);
                    acc1 = __builtin_amdgcn_mfma_f32_16x16x32_bf16(cal, cbh[1], acc1, 0, 0, 0);
                    acc2 = __builtin_amdgcn_mfma_f32_16x16x32_bf16(cal, cbh[2], acc2, 0, 0, 0);
                    acc3 = __builtin_amdgcn_mfma_f32_16x16x32_bf16(cal, cbh[3], acc3, 0, 0, 0);
                }
                cah = nah; cal = nal; chl = nhl;
                #pragma unroll
                for (int g = 0; g < 4; ++g) { cbh[g] = nbh[g]; cbl[g] = nbl[g]; }
            }

            if (wv == 1) {
                #pragma unroll
                for (int r = 0; r < 4; ++r) {
                    red[0][r][lane] = acc0[r];
                    red[1][r][lane] = acc1[r];
                    red[2][r][lane] = acc2[r];
                    red[3][r][lane] = acc3[r];
                }
            }
        }
        __syncthreads();
        if (active && wv == 0) {
            // reduce + bias + LSTM cell (all in-register; c never leaves VGPRs)
            ushort_t* Whi = layer ? (H1hi + (size_t)((p - 1) & 1) * HB) : (H0hi + (size_t)(p & 1) * HB);
            ushort_t* Wlo = layer ? (H1lo + (size_t)((p - 1) & 1) * HB) : (H0lo + (size_t)(p & 1) * HB);
            #pragma unroll
            for (int r = 0; r < 4; ++r) {
                float gi = acc0[r] + red[0][r][lane] + bg0;
                float gf = acc1[r] + red[1][r][lane] + bg1;
                float gg = acc2[r] + red[2][r][lane] + bg2;
                float go = acc3[r] + red[3][r][lane] + bg3;
                float ig = sigm(gi), fg = sigm(gf), gc = tanh_f(gg), og = sigm(go);
                float cn = fg * cst[r] + ig * gc;
                cst[r] = cn;
                float h = og * tanh_f(cn);
                int b = bt * 16 + (lane >> 4) * 4 + r;
                int cidx = u * 16 + (lane & 15);
                unsigned short hh = f2bf(h);
                float hf = bf2f(hh);
                unsigned short hl = f2bf(h - hf);
                Whi[(size_t)b * HDIM + cidx] = hh;
                Wlo[(size_t)b * HDIM + cidx] = hl;
            }
        }
        grid.sync();
    }

    // ---------- classifier: out = h1_final @ Wclf^T + bclf ----------
    if (wg == 0 && wv == 0) {
        int b = lane;
        float a0 = bclf[0], a1 = bclf[1];
        const ushort_t* hh = H1hi + HB;   // final h1 in slot 1
        const ushort_t* hl = H1lo + HB;
        #pragma unroll 8
        for (int k = 0; k < HDIM; ++k) {
            float h = bf2f(hh[(size_t)b * HDIM + k]) + bf2f(hl[(size_t)b * HDIM + k]);
            a0 = fmaf(h, Wclf[k], a0);
            a1 = fmaf(h, Wclf[HDIM + k], a1);
        }
        out[b * 2 + 0] = a0;
        out[b * 2 + 1] = a1;
    }
}

extern "C" void kernel_launch(void* const* d_in, const int* in_sizes, int n_in,
                              void* d_out, int out_size, void* d_ws, size_t ws_size,
                              hipStream_t stream) {
    const int*   x     = (const int*)d_in[0];
    const float* emb   = (const float*)d_in[1];
    const float* Wih0  = (const float*)d_in[2];
    const float* Whh0  = (const float*)d_in[3];
    const float* bias0 = (const float*)d_in[4];
    const float* Wih1  = (const float*)d_in[5];
    const float* Whh1  = (const float*)d_in[6];
    const float* bias1 = (const float*)d_in[7];
    const float* Wclf  = (const float*)d_in[8];
    const float* bclf  = (const float*)d_in[9];
    float* out = (float*)d_out;

    ushort_t* ws   = (ushort_t*)d_ws;
    ushort_t* XeHi = ws + OFF_XEHI;
    ushort_t* H0hi = ws + OFF_H0HI;
    ushort_t* H0lo = ws + OFF_H0LO;
    ushort_t* H1hi = ws + OFF_H1HI;
    ushort_t* H1lo = ws + OFF_H1LO;
    ushort_t* B0hi = ws + OFF_B0HI;
    ushort_t* B0lo = ws + OFF_B0LO;
    ushort_t* B1hi = ws + OFF_B1HI;
    ushort_t* B1lo = ws + OFF_B1LO;

    // 1) gather+convert embeddings: 1,048,576 threads
    xepack_kernel<<<4096, 256, 0, stream>>>(x, emb, XeHi);
    // 2) pack weights (hi/lo) to fragment order: 458,752 threads
    wpack_kernel<<<1793, 256, 0, stream>>>(Wih0, Whh0, Wih1, Whh1, B0hi, B0lo, B1hi, B1lo);
    // 3) zero h-state buffers (8 * HB ushorts = 131072 uints)
    zero_kernel<<<512, 256, 0, stream>>>((unsigned int*)H0hi, 8 * HB / 2);
    // 4) persistent cooperative LSTM
    void* args[] = {
        (void*)&XeHi,
        (void*)&H0hi, (void*)&H0lo, (void*)&H1hi, (void*)&H1lo,
        (void*)&B0hi, (void*)&B0lo, (void*)&B1hi, (void*)&B1lo,
        (void*)&bias0, (void*)&bias1,
        (void*)&Wclf, (void*)&bclf,
        (void*)&out
    };
    hipLaunchCooperativeKernel((void*)lstm_main, dim3(256), dim3(128), args, 0, stream);
}